// Round 3
// baseline (67.059 us; speedup 1.0000x reference)
//
#include <hip/hip_runtime.h>
#include <math.h>

#define B_   32
#define NB_  1024
#define H_   768
#define K_   384
#define C_   64

#define ROWS_   128              // rows per gate block
#define NSTEP_  (H_ / 32)        // 24 K-steps of 32
#define NT_     (K_ / 16)        // 24 n-tiles of 16

typedef __attribute__((ext_vector_type(8))) short  bf16x8;
typedef __attribute__((ext_vector_type(4))) float  f32x4;

__device__ __forceinline__ short f2bf(float f) {   // RNE fp32 -> bf16 bits
    unsigned u = __float_as_uint(f);
    unsigned r = (u + 0x7fffu + ((u >> 16) & 1u)) >> 16;
    return (short)r;
}

// ---------------------------------------------------------------------------
// Prep: W1 (768x384 fp32, n contiguous) -> bf16 swizzled into exact MFMA
// B-fragment order: frag (s,t): lane l, elem i = W1[s*32+(l>>4)*8+i][t*16+(l&15)]
// stored at ((s*24+t)*64 + l)*8 + i   (bf16 elements).
// ---------------------------------------------------------------------------
__global__ __launch_bounds__(256) void prep_w1(const float* __restrict__ W1,
                                               short* __restrict__ swz)
{
    int idx = blockIdx.x * 256 + threadIdx.x;        // 294912 = 768*384
    int k = idx / K_, n = idx % K_;
    float v = W1[idx];
    int s = k >> 5, g = (k >> 3) & 3, i = k & 7;
    int t = n >> 4, nn = n & 15;
    swz[((s * 24 + t) * 512) + (g * 16 + nn) * 8 + i] = f2bf(v);
}

// ---------------------------------------------------------------------------
// Gate MLP via MFMA. Block: 512 thr (8 waves) = 128 rows x 384 cols.
// Wave w: all 128 rows x cols [w*48, w*48+48)  -> acc[8][3] f32x4.
// Double-buffered LDS; A converted fp32->bf16 on staging; B copied from
// pre-swizzled global (contiguous, L2-resident).
// ---------------------------------------------------------------------------
__global__ __launch_bounds__(512, 2) void gate_kernel(
    const float* __restrict__ tokens, const short* __restrict__ swz,
    const float* __restrict__ b1, const float* __restrict__ W2,
    const float* __restrict__ b2, float* __restrict__ gate)
{
    __shared__ short As[2][8 * 512];    //  8 KiB/buf: frag f, lane l -> 8 bf16
    __shared__ short Bs[2][24 * 512];   // 24 KiB/buf: tile t, lane l -> 8 bf16
    __shared__ float red[8][128];       // epilogue partials

    const int tid  = threadIdx.x;
    const int lane = tid & 63;
    const int w    = tid >> 6;          // wave 0..7
    const int row0 = blockIdx.x * ROWS_;

    // per-thread staging geometry (constant across K-steps)
    const int arow = tid >> 2;          // 0..127
    const int akc  = tid & 3;           // which 8-k chunk of 32
    const size_t agbase = (size_t)(row0 + arow) * H_ + akc * 8;
    const int    aoff   = (arow >> 4) * 512 + (akc * 16 + (arow & 15)) * 8;

    f32x4 acc[8][3];
#pragma unroll
    for (int f = 0; f < 8; ++f)
#pragma unroll
        for (int j = 0; j < 3; ++j) acc[f][j] = (f32x4){0.f, 0.f, 0.f, 0.f};

    // ---- prologue: stage s = 0 into buf 0
    {
        float4 pa0 = *(const float4*)(tokens + agbase);
        float4 pa1 = *(const float4*)(tokens + agbase + 4);
        float4 pb0 = *(const float4*)((const char*)swz + 0 * 8192 + tid * 16);
        float4 pb1 = *(const float4*)((const char*)swz + 1 * 8192 + tid * 16);
        float4 pb2 = *(const float4*)((const char*)swz + 2 * 8192 + tid * 16);
        bf16x8 av = { f2bf(pa0.x), f2bf(pa0.y), f2bf(pa0.z), f2bf(pa0.w),
                      f2bf(pa1.x), f2bf(pa1.y), f2bf(pa1.z), f2bf(pa1.w) };
        *(bf16x8*)&As[0][aoff] = av;
        *(float4*)&Bs[0][0 * 4096 + tid * 8] = pb0;
        *(float4*)&Bs[0][1 * 4096 + tid * 8] = pb1;
        *(float4*)&Bs[0][2 * 4096 + tid * 8] = pb2;
    }
    __syncthreads();

    int buf = 0;
    for (int s = 0; s < NSTEP_; ++s) {
        float4 pa0, pa1, pb0, pb1, pb2;
        if (s < NSTEP_ - 1) {           // issue next-tile loads early (T14)
            const size_t ga = agbase + (size_t)(s + 1) * 32;
            pa0 = *(const float4*)(tokens + ga);
            pa1 = *(const float4*)(tokens + ga + 4);
            const char* gb = (const char*)swz + (size_t)(s + 1) * 24576;
            pb0 = *(const float4*)(gb + 0 * 8192 + tid * 16);
            pb1 = *(const float4*)(gb + 1 * 8192 + tid * 16);
            pb2 = *(const float4*)(gb + 2 * 8192 + tid * 16);
        }

        // compute on buf
        bf16x8 af[8];
#pragma unroll
        for (int f = 0; f < 8; ++f)
            af[f] = *(bf16x8*)&As[buf][f * 512 + lane * 8];
#pragma unroll
        for (int j = 0; j < 3; ++j) {
            bf16x8 bv = *(bf16x8*)&Bs[buf][(w * 3 + j) * 512 + lane * 8];
#pragma unroll
            for (int f = 0; f < 8; ++f)
                acc[f][j] = __builtin_amdgcn_mfma_f32_16x16x32_bf16(
                                af[f], bv, acc[f][j], 0, 0, 0);
        }

        if (s < NSTEP_ - 1) {           // late write into the other buffer
            bf16x8 av = { f2bf(pa0.x), f2bf(pa0.y), f2bf(pa0.z), f2bf(pa0.w),
                          f2bf(pa1.x), f2bf(pa1.y), f2bf(pa1.z), f2bf(pa1.w) };
            *(bf16x8*)&As[buf ^ 1][aoff] = av;
            *(float4*)&Bs[buf ^ 1][0 * 4096 + tid * 8] = pb0;
            *(float4*)&Bs[buf ^ 1][1 * 4096 + tid * 8] = pb1;
            *(float4*)&Bs[buf ^ 1][2 * 4096 + tid * 8] = pb2;
        }
        __syncthreads();
        buf ^= 1;
    }

    // ---- epilogue: gate[row] = b2 + sum_n tanh(h[row][n] + b1[n]) * W2[n]
    float ps[8][4];
#pragma unroll
    for (int f = 0; f < 8; ++f)
#pragma unroll
        for (int r = 0; r < 4; ++r) ps[f][r] = 0.f;

#pragma unroll
    for (int j = 0; j < 3; ++j) {
        const int n  = (w * 3 + j) * 16 + (lane & 15);
        const float bb = b1[n];
        const float ww = W2[n];
#pragma unroll
        for (int f = 0; f < 8; ++f)
#pragma unroll
            for (int r = 0; r < 4; ++r)
                ps[f][r] += tanhf(acc[f][j][r] + bb) * ww;
    }
    // reduce across the 16 lanes sharing a row (bits 0..3 of lane)
#pragma unroll
    for (int m = 1; m < 16; m <<= 1)
#pragma unroll
        for (int f = 0; f < 8; ++f)
#pragma unroll
            for (int r = 0; r < 4; ++r)
                ps[f][r] += __shfl_xor(ps[f][r], m, 64);

    if ((lane & 15) == 0) {
        const int rbase = (lane >> 4) * 4;
#pragma unroll
        for (int f = 0; f < 8; ++f)
#pragma unroll
            for (int r = 0; r < 4; ++r)
                red[w][f * 16 + rbase + r] = ps[f][r];
    }
    __syncthreads();
    if (tid < ROWS_) {
        float sgate = b2[0];
#pragma unroll
        for (int ww2 = 0; ww2 < 8; ++ww2) sgate += red[ww2][tid];
        gate[row0 + tid] = sgate;
    }
}

// ---------------------------------------------------------------------------
// Per-(b,c) masked softmax + weighted token sum. Deterministic ballot-based
// compaction so phase C only touches active blocks (~8 of 1024).
// ---------------------------------------------------------------------------
__global__ __launch_bounds__(256) void agg_kernel(
    const float* __restrict__ tokens, const int* __restrict__ active,
    const int* __restrict__ cmap, const float* __restrict__ gate,
    float* __restrict__ out_tok, float* __restrict__ out_act)
{
    __shared__ float wls[NB_];
    __shared__ float red[256];
    __shared__ int   idxs[NB_];
    __shared__ float wts[NB_];
    __shared__ int   gbase[17];

    const int b = blockIdx.x >> 6, c = blockIdx.x & 63;
    const int tid = threadIdx.x, lane = tid & 63, wid = tid >> 6;

    // phase A: masked gate + max
    float lmax = -INFINITY;
    for (int n = tid; n < NB_; n += 256) {
        const bool msk = (active[b * NB_ + n] != 0) && (cmap[n] == c);
        const float g  = msk ? gate[b * NB_ + n] : -INFINITY;
        wls[n] = g;
        lmax = fmaxf(lmax, g);
    }
    red[tid] = lmax; __syncthreads();
    for (int s = 128; s > 0; s >>= 1) {
        if (tid < s) red[tid] = fmaxf(red[tid], red[tid + s]);
        __syncthreads();
    }
    const float m = red[0]; __syncthreads();
    const float msafe = (m > -INFINITY) ? m : 0.f;

    // phase B: exp + sum
    float lsum = 0.f;
    for (int n = tid; n < NB_; n += 256) {
        const float g = wls[n];
        const float e = (g > -INFINITY) ? __expf(g - msafe) : 0.f;
        wls[n] = e; lsum += e;
    }
    red[tid] = lsum; __syncthreads();
    for (int s = 128; s > 0; s >>= 1) {
        if (tid < s) red[tid] += red[tid + s];
        __syncthreads();
    }
    const float ssum = red[0];
    const float inv  = (ssum > 0.f) ? 1.f / ssum : 0.f;
    __syncthreads();

    // deterministic compaction: group g = it*4+wid covers n = g*64+lane
#pragma unroll
    for (int it = 0; it < 4; ++it) {
        const int n = it * 256 + wid * 64 + lane;
        const unsigned long long mask = __ballot(wls[n] > 0.f);
        if (lane == 0) gbase[1 + it * 4 + wid] = __popcll(mask);
    }
    __syncthreads();
    if (tid == 0) {
        gbase[0] = 0;
        for (int i = 1; i <= 16; ++i) gbase[i] += gbase[i - 1];
    }
    __syncthreads();
#pragma unroll
    for (int it = 0; it < 4; ++it) {
        const int n = it * 256 + wid * 64 + lane;
        const float e = wls[n];
        const unsigned long long mask = __ballot(e > 0.f);
        if (e > 0.f) {
            const int pos = gbase[it * 4 + wid] +
                            __popcll(mask & ((1ull << lane) - 1ull));
            idxs[pos] = n;
            wts[pos]  = e * inv;
        }
    }
    __syncthreads();
    const int cnt = gbase[16];

    // phase C: weighted accumulation over the compacted list
    float a0 = 0.f, a1 = 0.f, a2 = 0.f;
    const float* tb = tokens + (size_t)b * NB_ * H_;
    for (int i = 0; i < cnt; ++i) {
        const float wv = wts[i];
        const float* t = tb + (size_t)idxs[i] * H_;
        a0 += wv * t[tid];
        a1 += wv * t[tid + 256];
        a2 += wv * t[tid + 512];
    }
    float* o = out_tok + ((size_t)(b * C_ + c)) * H_;
    o[tid]       = a0;
    o[tid + 256] = a1;
    o[tid + 512] = a2;
    if (tid == 0) out_act[b * C_ + c] = (m > -INFINITY) ? 1.f : 0.f;
}

// ---------------------------------------------------------------------------
extern "C" void kernel_launch(void* const* d_in, const int* in_sizes, int n_in,
                              void* d_out, int out_size, void* d_ws, size_t ws_size,
                              hipStream_t stream)
{
    const float* tokens = (const float*)d_in[0];
    const int*   active = (const int*)  d_in[1];
    const int*   cmap   = (const int*)  d_in[2];
    const float* W1     = (const float*)d_in[3];
    const float* b1     = (const float*)d_in[4];
    const float* W2     = (const float*)d_in[5];
    const float* b2     = (const float*)d_in[6];

    float* out      = (float*)d_out;
    float* out_act  = out + (size_t)B_ * C_ * H_;

    short* swz     = (short*)d_ws;                          // 589824 B
    float* gate_ws = (float*)((char*)d_ws + 589824);        // 131072 B

    prep_w1<<<(H_ * K_) / 256, 256, 0, stream>>>(W1, swz);
    gate_kernel<<<(B_ * NB_) / ROWS_, 512, 0, stream>>>(tokens, swz, b1, W2, b2, gate_ws);
    agg_kernel<<<B_ * C_, 256, 0, stream>>>(tokens, active, cmap, gate_ws, out, out_act);
}

// Round 4
// 66.664 us; speedup vs baseline: 1.0059x; 1.0059x over previous
//
#include <hip/hip_runtime.h>
#include <math.h>

#define B_   32
#define NB_  1024
#define H_   768
#define K_   384
#define C_   64

#define ROWS_   128              // rows per gate block
#define NSTEP_  (H_ / 32)        // 24 K-steps of 32
#define NT_     (K_ / 16)        // 24 n-tiles of 16

typedef __attribute__((ext_vector_type(8))) short  bf16x8;
typedef __attribute__((ext_vector_type(4))) float  f32x4;

__device__ __forceinline__ short f2bf(float f) {   // RNE fp32 -> bf16 bits
    unsigned u = __float_as_uint(f);
    unsigned r = (u + 0x7fffu + ((u >> 16) & 1u)) >> 16;
    return (short)r;
}

// ---------------------------------------------------------------------------
// Prep: W1 (768x384 fp32, n contiguous) -> bf16 swizzled into exact MFMA
// B-fragment order: frag (s,t): lane l, elem i = W1[s*32+(l>>4)*8+i][t*16+(l&15)]
// stored at ((s*24+t)*64 + l)*8 + i   (bf16 elements).
// ---------------------------------------------------------------------------
__global__ __launch_bounds__(256) void prep_w1(const float* __restrict__ W1,
                                               short* __restrict__ swz)
{
    int idx = blockIdx.x * 256 + threadIdx.x;        // 294912 = 768*384
    int k = idx / K_, n = idx % K_;
    float v = W1[idx];
    int s = k >> 5, g = (k >> 3) & 3, i = k & 7;
    int t = n >> 4, nn = n & 15;
    swz[((s * 24 + t) * 512) + (g * 16 + nn) * 8 + i] = f2bf(v);
}

// ---------------------------------------------------------------------------
// Gate MLP via MFMA. Block: 512 thr (8 waves) = 128 rows x 384 cols.
// Wave w: all 128 rows x cols [w*48, w*48+48)  -> acc[8][3] f32x4.
// Double-buffered LDS; A converted fp32->bf16 on staging; B copied from
// pre-swizzled global (contiguous, L2-resident).
// ---------------------------------------------------------------------------
__global__ __launch_bounds__(512, 2) void gate_kernel(
    const float* __restrict__ tokens, const short* __restrict__ swz,
    const float* __restrict__ b1, const float* __restrict__ W2,
    const float* __restrict__ b2, float* __restrict__ gate)
{
    __shared__ short As[2][8 * 512];    //  8 KiB/buf: frag f, lane l -> 8 bf16
    __shared__ short Bs[2][24 * 512];   // 24 KiB/buf: tile t, lane l -> 8 bf16
    __shared__ float red[8][128];       // epilogue partials

    const int tid  = threadIdx.x;
    const int lane = tid & 63;
    const int w    = tid >> 6;          // wave 0..7
    const int row0 = blockIdx.x * ROWS_;

    // per-thread staging geometry (constant across K-steps)
    const int arow = tid >> 2;          // 0..127
    const int akc  = tid & 3;           // which 8-k chunk of 32
    const size_t agbase = (size_t)(row0 + arow) * H_ + akc * 8;
    const int    aoff   = (arow >> 4) * 512 + (akc * 16 + (arow & 15)) * 8;

    f32x4 acc[8][3];
#pragma unroll
    for (int f = 0; f < 8; ++f)
#pragma unroll
        for (int j = 0; j < 3; ++j) acc[f][j] = (f32x4){0.f, 0.f, 0.f, 0.f};

    // ---- prologue: stage s = 0 into buf 0
    {
        float4 pa0 = *(const float4*)(tokens + agbase);
        float4 pa1 = *(const float4*)(tokens + agbase + 4);
        float4 pb0 = *(const float4*)((const char*)swz + 0 * 8192 + tid * 16);
        float4 pb1 = *(const float4*)((const char*)swz + 1 * 8192 + tid * 16);
        float4 pb2 = *(const float4*)((const char*)swz + 2 * 8192 + tid * 16);
        bf16x8 av = { f2bf(pa0.x), f2bf(pa0.y), f2bf(pa0.z), f2bf(pa0.w),
                      f2bf(pa1.x), f2bf(pa1.y), f2bf(pa1.z), f2bf(pa1.w) };
        *(bf16x8*)&As[0][aoff] = av;
        *(float4*)&Bs[0][0 * 4096 + tid * 8] = pb0;
        *(float4*)&Bs[0][1 * 4096 + tid * 8] = pb1;
        *(float4*)&Bs[0][2 * 4096 + tid * 8] = pb2;
    }
    __syncthreads();

    int buf = 0;
    for (int s = 0; s < NSTEP_; ++s) {
        float4 pa0, pa1, pb0, pb1, pb2;
        if (s < NSTEP_ - 1) {           // issue next-tile loads early (T14)
            const size_t ga = agbase + (size_t)(s + 1) * 32;
            pa0 = *(const float4*)(tokens + ga);
            pa1 = *(const float4*)(tokens + ga + 4);
            const char* gb = (const char*)swz + (size_t)(s + 1) * 24576;
            pb0 = *(const float4*)(gb + 0 * 8192 + tid * 16);
            pb1 = *(const float4*)(gb + 1 * 8192 + tid * 16);
            pb2 = *(const float4*)(gb + 2 * 8192 + tid * 16);
        }

        // compute on buf
        bf16x8 af[8];
#pragma unroll
        for (int f = 0; f < 8; ++f)
            af[f] = *(bf16x8*)&As[buf][f * 512 + lane * 8];
#pragma unroll
        for (int j = 0; j < 3; ++j) {
            bf16x8 bv = *(bf16x8*)&Bs[buf][(w * 3 + j) * 512 + lane * 8];
#pragma unroll
            for (int f = 0; f < 8; ++f)
                acc[f][j] = __builtin_amdgcn_mfma_f32_16x16x32_bf16(
                                af[f], bv, acc[f][j], 0, 0, 0);
        }

        if (s < NSTEP_ - 1) {           // late write into the other buffer
            bf16x8 av = { f2bf(pa0.x), f2bf(pa0.y), f2bf(pa0.z), f2bf(pa0.w),
                          f2bf(pa1.x), f2bf(pa1.y), f2bf(pa1.z), f2bf(pa1.w) };
            *(bf16x8*)&As[buf ^ 1][aoff] = av;
            *(float4*)&Bs[buf ^ 1][0 * 4096 + tid * 8] = pb0;
            *(float4*)&Bs[buf ^ 1][1 * 4096 + tid * 8] = pb1;
            *(float4*)&Bs[buf ^ 1][2 * 4096 + tid * 8] = pb2;
        }
        __syncthreads();
        buf ^= 1;
    }

    // ---- epilogue: gate[row] = b2 + sum_n tanh(h[row][n] + b1[n]) * W2[n]
    float ps[8][4];
#pragma unroll
    for (int f = 0; f < 8; ++f)
#pragma unroll
        for (int r = 0; r < 4; ++r) ps[f][r] = 0.f;

#pragma unroll
    for (int j = 0; j < 3; ++j) {
        const int n  = (w * 3 + j) * 16 + (lane & 15);
        const float bb = b1[n];
        const float ww = W2[n];
#pragma unroll
        for (int f = 0; f < 8; ++f)
#pragma unroll
            for (int r = 0; r < 4; ++r)
                ps[f][r] += tanhf(acc[f][j][r] + bb) * ww;
    }
    // reduce across the 16 lanes sharing a row (bits 0..3 of lane)
#pragma unroll
    for (int m = 1; m < 16; m <<= 1)
#pragma unroll
        for (int f = 0; f < 8; ++f)
#pragma unroll
            for (int r = 0; r < 4; ++r)
                ps[f][r] += __shfl_xor(ps[f][r], m, 64);

    if ((lane & 15) == 0) {
        const int rbase = (lane >> 4) * 4;
#pragma unroll
        for (int f = 0; f < 8; ++f)
#pragma unroll
            for (int r = 0; r < 4; ++r)
                red[w][f * 16 + rbase + r] = ps[f][r];
    }
    __syncthreads();
    if (tid < ROWS_) {
        float sgate = b2[0];
#pragma unroll
        for (int ww2 = 0; ww2 < 8; ++ww2) sgate += red[ww2][tid];
        gate[row0 + tid] = sgate;
    }
}

// ---------------------------------------------------------------------------
// Per-(b,c) masked softmax + weighted token sum. Deterministic ballot-based
// compaction so phase C only touches active blocks (~8 of 1024).
// ---------------------------------------------------------------------------
__global__ __launch_bounds__(256) void agg_kernel(
    const float* __restrict__ tokens, const int* __restrict__ active,
    const int* __restrict__ cmap, const float* __restrict__ gate,
    float* __restrict__ out_tok, float* __restrict__ out_act)
{
    __shared__ float wls[NB_];
    __shared__ float red[256];
    __shared__ int   idxs[NB_];
    __shared__ float wts[NB_];
    __shared__ int   gbase[17];

    const int b = blockIdx.x >> 6, c = blockIdx.x & 63;
    const int tid = threadIdx.x, lane = tid & 63, wid = tid >> 6;

    // phase A: masked gate + max
    float lmax = -INFINITY;
    for (int n = tid; n < NB_; n += 256) {
        const bool msk = (active[b * NB_ + n] != 0) && (cmap[n] == c);
        const float g  = msk ? gate[b * NB_ + n] : -INFINITY;
        wls[n] = g;
        lmax = fmaxf(lmax, g);
    }
    red[tid] = lmax; __syncthreads();
    for (int s = 128; s > 0; s >>= 1) {
        if (tid < s) red[tid] = fmaxf(red[tid], red[tid + s]);
        __syncthreads();
    }
    const float m = red[0]; __syncthreads();
    const float msafe = (m > -INFINITY) ? m : 0.f;

    // phase B: exp + sum
    float lsum = 0.f;
    for (int n = tid; n < NB_; n += 256) {
        const float g = wls[n];
        const float e = (g > -INFINITY) ? __expf(g - msafe) : 0.f;
        wls[n] = e; lsum += e;
    }
    red[tid] = lsum; __syncthreads();
    for (int s = 128; s > 0; s >>= 1) {
        if (tid < s) red[tid] += red[tid + s];
        __syncthreads();
    }
    const float ssum = red[0];
    const float inv  = (ssum > 0.f) ? 1.f / ssum : 0.f;
    __syncthreads();

    // deterministic compaction: group g = it*4+wid covers n = g*64+lane
#pragma unroll
    for (int it = 0; it < 4; ++it) {
        const int n = it * 256 + wid * 64 + lane;
        const unsigned long long mask = __ballot(wls[n] > 0.f);
        if (lane == 0) gbase[1 + it * 4 + wid] = __popcll(mask);
    }
    __syncthreads();
    if (tid == 0) {
        gbase[0] = 0;
        for (int i = 1; i <= 16; ++i) gbase[i] += gbase[i - 1];
    }
    __syncthreads();
#pragma unroll
    for (int it = 0; it < 4; ++it) {
        const int n = it * 256 + wid * 64 + lane;
        const float e = wls[n];
        const unsigned long long mask = __ballot(e > 0.f);
        if (e > 0.f) {
            const int pos = gbase[it * 4 + wid] +
                            __popcll(mask & ((1ull << lane) - 1ull));
            idxs[pos] = n;
            wts[pos]  = e * inv;
        }
    }
    __syncthreads();
    const int cnt = gbase[16];

    // phase C: weighted accumulation over the compacted list
    float a0 = 0.f, a1 = 0.f, a2 = 0.f;
    const float* tb = tokens + (size_t)b * NB_ * H_;
    for (int i = 0; i < cnt; ++i) {
        const float wv = wts[i];
        const float* t = tb + (size_t)idxs[i] * H_;
        a0 += wv * t[tid];
        a1 += wv * t[tid + 256];
        a2 += wv * t[tid + 512];
    }
    float* o = out_tok + ((size_t)(b * C_ + c)) * H_;
    o[tid]       = a0;
    o[tid + 256] = a1;
    o[tid + 512] = a2;
    if (tid == 0) out_act[b * C_ + c] = (m > -INFINITY) ? 1.f : 0.f;
}

// ---------------------------------------------------------------------------
extern "C" void kernel_launch(void* const* d_in, const int* in_sizes, int n_in,
                              void* d_out, int out_size, void* d_ws, size_t ws_size,
                              hipStream_t stream)
{
    const float* tokens = (const float*)d_in[0];
    const int*   active = (const int*)  d_in[1];
    const int*   cmap   = (const int*)  d_in[2];
    const float* W1     = (const float*)d_in[3];
    const float* b1     = (const float*)d_in[4];
    const float* W2     = (const float*)d_in[5];
    const float* b2     = (const float*)d_in[6];

    float* out      = (float*)d_out;
    float* out_act  = out + (size_t)B_ * C_ * H_;

    short* swz     = (short*)d_ws;                          // 589824 B
    float* gate_ws = (float*)((char*)d_ws + 589824);        // 131072 B

    prep_w1<<<(H_ * K_) / 256, 256, 0, stream>>>(W1, swz);
    gate_kernel<<<(B_ * NB_) / ROWS_, 512, 0, stream>>>(tokens, swz, b1, W2, b2, gate_ws);
    agg_kernel<<<B_ * C_, 256, 0, stream>>>(tokens, active, cmap, gate_ws, out, out_act);
}

// Round 5
// 55.943 us; speedup vs baseline: 1.1987x; 1.1917x over previous
//
#include <hip/hip_runtime.h>
#include <math.h>

#define B_    32
#define NB_   1024
#define H_    768
#define K_    384
#define C_    64
#define ROWS_ 128
#define NSTEP_ 24               // 24 K-steps of 32

typedef __attribute__((ext_vector_type(8))) short bf16x8;
typedef __attribute__((ext_vector_type(4))) float f32x4;

__device__ __forceinline__ short f2bf(float f) {   // RNE fp32 -> bf16 bits
    unsigned u = __float_as_uint(f);
    unsigned r = (u + 0x7fffu + ((u >> 16) & 1u)) >> 16;
    return (short)r;
}
__device__ __forceinline__ float ftanh(float x) {  // tanh = 1 - 2/(e^2x + 1)
    float e = __expf(2.f * x);
    return 1.f - 2.f * __builtin_amdgcn_rcpf(e + 1.f);
}

// ---------------------------------------------------------------------------
// W1 (768x384 fp32) -> bf16 swizzled to exact MFMA B-fragment order.
// frag (s,t): lane l, elem i = W1[s*32+(l>>4)*8+i][t*16+(l&15)]
// ---------------------------------------------------------------------------
__global__ __launch_bounds__(256) void prep_w1(const float* __restrict__ W1,
                                               short* __restrict__ swz)
{
    int idx = blockIdx.x * 256 + threadIdx.x;
    int k = idx / K_, n = idx % K_;
    float v = W1[idx];
    int s = k >> 5, g = (k >> 3) & 3, i = k & 7;
    int t = n >> 4, nn = n & 15;
    swz[((s * 24 + t) * 512) + (g * 16 + nn) * 8 + i] = f2bf(v);
}

// ---------------------------------------------------------------------------
// Per-batch compaction of active rows. 1 block per b, 1024 threads.
// list[b*NB+i] = n for i < cnt[b]; tail filled with 0 (benign duplicates).
// ---------------------------------------------------------------------------
__global__ __launch_bounds__(1024) void compact_kernel(
    const int* __restrict__ active, int* __restrict__ list, int* __restrict__ cnt)
{
    __shared__ int wsum[16];
    __shared__ int wbase[17];
    const int b = blockIdx.x, tid = threadIdx.x, lane = tid & 63, wid = tid >> 6;
    const int flag = active[b * NB_ + tid] != 0;
    const unsigned long long m = __ballot(flag);
    if (lane == 0) wsum[wid] = __popcll(m);
    __syncthreads();
    if (tid == 0) {
        int r = 0;
        for (int i = 0; i < 16; ++i) { wbase[i] = r; r += wsum[i]; }
        wbase[16] = r;
        cnt[b] = r;
    }
    __syncthreads();
    const int total = wbase[16];
    if (flag) {
        const int pos = wbase[wid] + __popcll(m & ((1ull << lane) - 1ull));
        list[b * NB_ + pos] = tid;
    }
    if (tid >= total) list[b * NB_ + tid] = 0;
}

// ---------------------------------------------------------------------------
// Gate MLP via MFMA over compacted active rows.
// Block: 512 thr (8 waves) = 128 list-rows x 384 cols; wave w: cols [w*48,w*48+48).
// A: fp32 global -> regs (2-step prefetch) -> bf16 LDS (double buffer, XOR-swz).
// B: direct global reads of pre-swizzled frags (L2-resident), 1-step prefetch.
// Raw s_barrier + counted waits: global loads stay in flight across barriers.
// ---------------------------------------------------------------------------
__global__ __launch_bounds__(512) void gate_kernel(
    const float* __restrict__ tokens, const short* __restrict__ swz,
    const float* __restrict__ b1, const float* __restrict__ W2,
    const float* __restrict__ b2, const int* __restrict__ list,
    const int* __restrict__ cnt, float* __restrict__ gate)
{
    __shared__ __align__(16) short As[2][4096];   // 2 x 8 KiB bf16 (128x32)
    __shared__ float red[8][128];

    const int b = blockIdx.x >> 3;
    const int chunk = blockIdx.x & 7;
    if (chunk * ROWS_ >= cnt[b]) return;          // uniform early-exit

    const int tid = threadIdx.x;
    const int lane = tid & 63;
    const int w = tid >> 6;

    const int arow = tid >> 2;                    // 0..127 local row
    const int akc  = tid & 3;                     // 8-float chunk of 32
    const int nrow = list[b * NB_ + chunk * ROWS_ + arow];
    const float* aptr = tokens + ((size_t)b * NB_ + nrow) * H_ + akc * 8;

    // LDS addr: frag f=arow>>4, linear idx q=akc*16+(arow&15), XOR-swizzled
    const int aoff = (arow >> 4) * 512 + (((akc * 16 + (arow & 15)) ^ (akc * 2)) * 8);
    const int roff = (lane ^ ((lane >> 4) * 2)) * 8;
    const short* bbase = swz + (w * 3) * 512 + lane * 8;

    f32x4 acc[3][8];
#pragma unroll
    for (int j = 0; j < 3; ++j)
#pragma unroll
        for (int f = 0; f < 8; ++f) acc[j][f] = (f32x4){0.f, 0.f, 0.f, 0.f};

    // ---- prologue: ld[0]->pe, ld[1]->po, B[0]->be; write step-0 LDS
    float4 pe0 = *(const float4*)(aptr);
    float4 pe1 = *(const float4*)(aptr + 4);
    float4 po0 = *(const float4*)(aptr + 32);
    float4 po1 = *(const float4*)(aptr + 36);
    bf16x8 be0 = *(const bf16x8*)(bbase);
    bf16x8 be1 = *(const bf16x8*)(bbase + 512);
    bf16x8 be2 = *(const bf16x8*)(bbase + 1024);
    bf16x8 bo0 = be0, bo1 = be1, bo2 = be2;
    {
        bf16x8 av = {f2bf(pe0.x), f2bf(pe0.y), f2bf(pe0.z), f2bf(pe0.w),
                     f2bf(pe1.x), f2bf(pe1.y), f2bf(pe1.z), f2bf(pe1.w)};
        *(bf16x8*)&As[0][aoff] = av;
    }
    asm volatile("s_waitcnt lgkmcnt(0)" ::: "memory");
    __builtin_amdgcn_s_barrier();
    __builtin_amdgcn_sched_barrier(0);

    // iter S: issue ld[S+2]->PA, cvt+ds_write QA (=ld[S+1]) -> buf[(S+1)&1],
    // prefetch B[S+1]->BN, compute step S from buf[S&1] with BC. One raw
    // barrier per iter; vmem stays in flight (counted waits on reg use).
#define GATE_ITER(S, PA0, PA1, QA0, QA1, BC0, BC1, BC2, BN0, BN1, BN2)        \
    do {                                                                      \
        if ((S) + 2 < NSTEP_) {                                               \
            PA0 = *(const float4*)(aptr + ((S) + 2) * 32);                    \
            PA1 = *(const float4*)(aptr + ((S) + 2) * 32 + 4);                \
        }                                                                     \
        if ((S) + 1 < NSTEP_) {                                               \
            const short* bp = bbase + ((S) + 1) * 12288;                      \
            BN0 = *(const bf16x8*)(bp);                                       \
            BN1 = *(const bf16x8*)(bp + 512);                                 \
            BN2 = *(const bf16x8*)(bp + 1024);                                \
            bf16x8 av = {f2bf(QA0.x), f2bf(QA0.y), f2bf(QA0.z), f2bf(QA0.w),  \
                         f2bf(QA1.x), f2bf(QA1.y), f2bf(QA1.z), f2bf(QA1.w)}; \
            *(bf16x8*)&As[((S) + 1) & 1][aoff] = av;                          \
        }                                                                     \
        _Pragma("unroll")                                                     \
        for (int f = 0; f < 8; ++f) {                                         \
            bf16x8 af = *(const bf16x8*)&As[(S) & 1][f * 512 + roff];         \
            acc[0][f] = __builtin_amdgcn_mfma_f32_16x16x32_bf16(af, BC0, acc[0][f], 0, 0, 0); \
            acc[1][f] = __builtin_amdgcn_mfma_f32_16x16x32_bf16(af, BC1, acc[1][f], 0, 0, 0); \
            acc[2][f] = __builtin_amdgcn_mfma_f32_16x16x32_bf16(af, BC2, acc[2][f], 0, 0, 0); \
        }                                                                     \
        asm volatile("s_waitcnt lgkmcnt(0)" ::: "memory");                    \
        __builtin_amdgcn_s_barrier();                                         \
        __builtin_amdgcn_sched_barrier(0);                                    \
    } while (0)

    for (int s = 0; s < NSTEP_; s += 2) {
        GATE_ITER(s,     pe0, pe1, po0, po1, be0, be1, be2, bo0, bo1, bo2);
        GATE_ITER(s + 1, po0, po1, pe0, pe1, bo0, bo1, bo2, be0, be1, be2);
    }
#undef GATE_ITER

    // ---- epilogue: gate[row] = b2 + sum_n tanh(h + b1[n]) * W2[n]
    float ps[8][4];
#pragma unroll
    for (int f = 0; f < 8; ++f)
#pragma unroll
        for (int r = 0; r < 4; ++r) ps[f][r] = 0.f;

#pragma unroll
    for (int j = 0; j < 3; ++j) {
        const int n = (w * 3 + j) * 16 + (lane & 15);
        const float bb = b1[n];
        const float ww = W2[n];
#pragma unroll
        for (int f = 0; f < 8; ++f)
#pragma unroll
            for (int r = 0; r < 4; ++r)
                ps[f][r] += ftanh(acc[j][f][r] + bb) * ww;
    }
#pragma unroll
    for (int m = 1; m < 16; m <<= 1)
#pragma unroll
        for (int f = 0; f < 8; ++f)
#pragma unroll
            for (int r = 0; r < 4; ++r)
                ps[f][r] += __shfl_xor(ps[f][r], m, 64);

    if ((lane & 15) == 0) {
        const int rbase = (lane >> 4) * 4;
#pragma unroll
        for (int f = 0; f < 8; ++f)
#pragma unroll
            for (int r = 0; r < 4; ++r)
                red[w][f * 16 + rbase + r] = ps[f][r];
    }
    __syncthreads();
    if (tid < ROWS_) {
        float sg = b2[0];
#pragma unroll
        for (int q = 0; q < 8; ++q) sg += red[q][tid];
        gate[b * NB_ + list[b * NB_ + chunk * ROWS_ + tid]] = sg;
    }
}

// ---------------------------------------------------------------------------
// Per-(b,c) masked softmax + weighted token sum (unchanged, known-good).
// ---------------------------------------------------------------------------
__global__ __launch_bounds__(256) void agg_kernel(
    const float* __restrict__ tokens, const int* __restrict__ active,
    const int* __restrict__ cmap, const float* __restrict__ gate,
    float* __restrict__ out_tok, float* __restrict__ out_act)
{
    __shared__ float wls[NB_];
    __shared__ float red[256];
    __shared__ int   idxs[NB_];
    __shared__ float wts[NB_];
    __shared__ int   gbase[17];

    const int b = blockIdx.x >> 6, c = blockIdx.x & 63;
    const int tid = threadIdx.x, lane = tid & 63, wid = tid >> 6;

    float lmax = -INFINITY;
    for (int n = tid; n < NB_; n += 256) {
        const bool msk = (active[b * NB_ + n] != 0) && (cmap[n] == c);
        const float g  = msk ? gate[b * NB_ + n] : -INFINITY;
        wls[n] = g;
        lmax = fmaxf(lmax, g);
    }
    red[tid] = lmax; __syncthreads();
    for (int s = 128; s > 0; s >>= 1) {
        if (tid < s) red[tid] = fmaxf(red[tid], red[tid + s]);
        __syncthreads();
    }
    const float m = red[0]; __syncthreads();
    const float msafe = (m > -INFINITY) ? m : 0.f;

    float lsum = 0.f;
    for (int n = tid; n < NB_; n += 256) {
        const float g = wls[n];
        const float e = (g > -INFINITY) ? __expf(g - msafe) : 0.f;
        wls[n] = e; lsum += e;
    }
    red[tid] = lsum; __syncthreads();
    for (int s = 128; s > 0; s >>= 1) {
        if (tid < s) red[tid] += red[tid + s];
        __syncthreads();
    }
    const float ssum = red[0];
    const float inv  = (ssum > 0.f) ? 1.f / ssum : 0.f;
    __syncthreads();

#pragma unroll
    for (int it = 0; it < 4; ++it) {
        const int n = it * 256 + wid * 64 + lane;
        const unsigned long long mask = __ballot(wls[n] > 0.f);
        if (lane == 0) gbase[1 + it * 4 + wid] = __popcll(mask);
    }
    __syncthreads();
    if (tid == 0) {
        gbase[0] = 0;
        for (int i = 1; i <= 16; ++i) gbase[i] += gbase[i - 1];
    }
    __syncthreads();
#pragma unroll
    for (int it = 0; it < 4; ++it) {
        const int n = it * 256 + wid * 64 + lane;
        const float e = wls[n];
        const unsigned long long mask = __ballot(e > 0.f);
        if (e > 0.f) {
            const int pos = gbase[it * 4 + wid] +
                            __popcll(mask & ((1ull << lane) - 1ull));
            idxs[pos] = n;
            wts[pos]  = e * inv;
        }
    }
    __syncthreads();
    const int cnt = gbase[16];

    float a0 = 0.f, a1 = 0.f, a2 = 0.f;
    const float* tb = tokens + (size_t)b * NB_ * H_;
    for (int i = 0; i < cnt; ++i) {
        const float wv = wts[i];
        const float* t = tb + (size_t)idxs[i] * H_;
        a0 += wv * t[tid];
        a1 += wv * t[tid + 256];
        a2 += wv * t[tid + 512];
    }
    float* o = out_tok + ((size_t)(b * C_ + c)) * H_;
    o[tid]       = a0;
    o[tid + 256] = a1;
    o[tid + 512] = a2;
    if (tid == 0) out_act[b * C_ + c] = (m > -INFINITY) ? 1.f : 0.f;
}

// ---------------------------------------------------------------------------
extern "C" void kernel_launch(void* const* d_in, const int* in_sizes, int n_in,
                              void* d_out, int out_size, void* d_ws, size_t ws_size,
                              hipStream_t stream)
{
    const float* tokens = (const float*)d_in[0];
    const int*   active = (const int*)  d_in[1];
    const int*   cmap   = (const int*)  d_in[2];
    const float* W1     = (const float*)d_in[3];
    const float* b1     = (const float*)d_in[4];
    const float* W2     = (const float*)d_in[5];
    const float* b2     = (const float*)d_in[6];

    float* out      = (float*)d_out;
    float* out_act  = out + (size_t)B_ * C_ * H_;

    short* swz     = (short*)d_ws;                          // 589824 B
    float* gate_ws = (float*)((char*)d_ws + 589824);        // 131072 B
    int*   list    = (int*)  ((char*)d_ws + 720896);        // 131072 B
    int*   cntb    = (int*)  ((char*)d_ws + 851968);        // 128 B

    compact_kernel<<<B_, 1024, 0, stream>>>(active, list, cntb);
    prep_w1<<<(H_ * K_) / 256, 256, 0, stream>>>(W1, swz);
    gate_kernel<<<B_ * 8, 512, 0, stream>>>(tokens, swz, b1, W2, b2, list, cntb, gate_ws);
    agg_kernel<<<B_ * C_, 256, 0, stream>>>(tokens, active, cmap, gate_ws, out, out_act);
}